// Round 2
// baseline (486.882 us; speedup 1.0000x reference)
//
#include <hip/hip_runtime.h>
#include <hip/hip_bf16.h>
#include <math.h>

typedef _Float16 f16;
typedef __attribute__((ext_vector_type(8))) _Float16 f16x8;
typedef __attribute__((ext_vector_type(4))) _Float16 f16x4;
typedef __attribute__((ext_vector_type(4))) float f32x4;

#define EMBED 1024
#define NHEADS 16
#define HDIM 64
#define BATCH 2
#define SEQ 2048
#define BS 4096  // BATCH*SEQ
#define LOG2E 1.4426950408889634f

// ---------------- ws layout (bytes) ----------------
// Xh:      0         (BS*EMBED f16       = 8388608)
// Wqkv_t:  8388608   (3072*1024 f16      = 6291456)
// Wout_t:  14680064  (1024*1024 f16      = 2097152)
// Qw:      16777216  (32*2048*64 f16     = 8388608)   [bh][s][d], pre-scaled by log2e
// Kw:      25165824  [bh][s][d]
// VTw:     33554432  [bh][d][s]  (transposed!)
// Ow:      41943040  ([B][S][H*64] f16   = 8388608)
// btab:    50331648  (16*4095 f32, pre-scaled by log2e)

__device__ __forceinline__ f32x4 mfma16x32(f16x8 a, f16x8 b, f32x4 c) {
  return __builtin_amdgcn_mfma_f32_16x16x32_f16(a, b, c, 0, 0, 0);
}
__device__ __forceinline__ f32x4 mfma16x16(f16x4 a, f16x4 b, f32x4 c) {
  return __builtin_amdgcn_mfma_f32_16x16x16f16(a, b, c, 0, 0, 0);
}

// ---------------- cast fp32 -> fp16 ----------------
__global__ void cast_x_kernel(const float* __restrict__ src, f16* __restrict__ dst) {
  int i = (blockIdx.x * 256 + threadIdx.x) * 4;
  float4 v = *(const float4*)(src + i);
  f16x4 o = { (f16)v.x, (f16)v.y, (f16)v.z, (f16)v.w };
  *(f16x4*)(dst + i) = o;
}

// ------------- transpose + cast: in[K][N] fp32 -> out[N][K] fp16 -------------
__global__ void transpose_cast_kernel(const float* __restrict__ in, f16* __restrict__ out,
                                      int K, int N) {
  __shared__ float tile[32][33];
  int n0 = blockIdx.x * 32, k0 = blockIdx.y * 32;
  int tx = threadIdx.x & 31, ty = threadIdx.x >> 5;  // 256 thr: ty 0..7
#pragma unroll
  for (int r = ty; r < 32; r += 8) tile[r][tx] = in[(size_t)(k0 + r) * N + n0 + tx];
  __syncthreads();
#pragma unroll
  for (int r = ty; r < 32; r += 8) out[(size_t)(n0 + r) * K + k0 + tx] = (f16)tile[tx][r];
}

// ------------- relative-position bias table: btab[h][rp+2047], scaled by log2e -------------
__global__ void bias_table_kernel(const float* __restrict__ rel_emb, float* __restrict__ btab) {
  int idx = blockIdx.x * 256 + threadIdx.x;  // 0..4094
  if (idx >= 4095) return;
  int rp = idx - 2047;                       // rp = k - q
  int rb = rp > 0 ? 16 : 0;
  int arp = rp < 0 ? -rp : rp;
  int loc;
  if (arp < 8) {
    loc = arp;
  } else {
    float lr = logf((float)arp * 0.125f) * (1.0f / 2.7725887222397811f);
    int t = 8 + (int)(lr * 8.0f);
    loc = t < 15 ? t : 15;
  }
  int bucket = rb + loc;
#pragma unroll
  for (int h = 0; h < 16; h++) btab[h * 4095 + idx] = rel_emb[bucket * 16 + h] * LOG2E;
}

// ------------- shared GEMM core: C[128x128] = A[MxK] * Bt[NxK]^T -------------
__device__ __forceinline__ void gemm_core(const f16* __restrict__ A, const f16* __restrict__ Bt,
                                          int m0, int n0, int Kdim, f32x4 (&acc)[4][4]) {
  __shared__ __align__(16) f16 As[128 * 40];  // [m][k] stride 40
  __shared__ __align__(16) f16 Bs[128 * 40];  // [n][k] stride 40

  int tid = threadIdx.x;
  int lane = tid & 63, wave = tid >> 6;
  int l15 = lane & 15, quad = lane >> 4;
  int wr = (wave >> 1) * 64, wc = (wave & 1) * 64;

#pragma unroll
  for (int i = 0; i < 4; i++)
#pragma unroll
    for (int j = 0; j < 4; j++) acc[i][j] = f32x4{0.f, 0.f, 0.f, 0.f};

  for (int kt = 0; kt < Kdim / 32; kt++) {
    int kk = kt * 32;
#pragma unroll
    for (int c = 0; c < 2; c++) {
      int i = c * 256 + tid;            // 0..511 chunks of 8 f16
      int row = i >> 2, cc = (i & 3) * 8;
      int4 av = *(const int4*)(A + (size_t)(m0 + row) * Kdim + kk + cc);
      int4 bv = *(const int4*)(Bt + (size_t)(n0 + row) * Kdim + kk + cc);
      *(int4*)(&As[row * 40 + cc]) = av;
      *(int4*)(&Bs[row * 40 + cc]) = bv;
    }
    __syncthreads();
    f16x8 af[4], bf[4];
#pragma unroll
    for (int i = 0; i < 4; i++) af[i] = *(const f16x8*)(&As[(wr + i * 16 + l15) * 40 + quad * 8]);
#pragma unroll
    for (int j = 0; j < 4; j++) bf[j] = *(const f16x8*)(&Bs[(wc + j * 16 + l15) * 40 + quad * 8]);
#pragma unroll
    for (int i = 0; i < 4; i++)
#pragma unroll
      for (int j = 0; j < 4; j++) acc[i][j] = mfma16x32(af[i], bf[j], acc[i][j]);
    __syncthreads();
  }
}

// ------------- GEMM1: qkv = Xh @ Wqkv_t^T; Q scaled by log2e; V stored transposed -------------
__global__ __launch_bounds__(256, 2) void gemm_qkv_kernel(
    const f16* __restrict__ Xh, const f16* __restrict__ Wt,
    f16* __restrict__ Q, f16* __restrict__ K_, f16* __restrict__ VT) {
  f32x4 acc[4][4];
  int m0 = blockIdx.y * 128, n0 = blockIdx.x * 128;
  gemm_core(Xh, Wt, m0, n0, 1024, acc);

  int lane = threadIdx.x & 63, wave = threadIdx.x >> 6;
  int l15 = lane & 15, quad = lane >> 4;
  int wr = (wave >> 1) * 64, wc = (wave & 1) * 64;
  int nq = n0 + wc;          // 64-aligned; uniform per wave quadrant
  int which = nq >> 10;
  int h = (nq >> 6) & 15;
  int b = m0 >> 11;          // 128-tile never crosses batch boundary

  if (which == 2) {
    // V transposed: VT[bh][d][s], packed f16x4 along s
    f16* vbase = VT + ((size_t)(b * 16 + h) * 64) * 2048;
    int s0 = (m0 & 2047) + wr + quad * 4;
#pragma unroll
    for (int j = 0; j < 4; j++) {
      int d = j * 16 + l15;
#pragma unroll
      for (int i = 0; i < 4; i++) {
        f16x4 pk = { (f16)acc[i][j][0], (f16)acc[i][j][1], (f16)acc[i][j][2], (f16)acc[i][j][3] };
        *(f16x4*)(vbase + (size_t)d * 2048 + s0 + i * 16) = pk;
      }
    }
  } else {
    f16* base = (which == 0) ? Q : K_;
    float sc = (which == 0) ? LOG2E : 1.0f;
#pragma unroll
    for (int i = 0; i < 4; i++) {
#pragma unroll
      for (int j = 0; j < 4; j++) {
        int d = j * 16 + l15;
#pragma unroll
        for (int r = 0; r < 4; r++) {
          int m = m0 + wr + i * 16 + quad * 4 + r;
          int s = m & 2047;
          base[(((size_t)(b * 16 + h) * 2048 + s) << 6) + d] = (f16)(acc[i][j][r] * sc);
        }
      }
    }
  }
}

// ------------- flash attention, no LDS staging in hot loop -------------
// Computes S^T per tile: mfma(kf,qf) -> C[key][q]; C-frag of S^T == A-frag of P
// for 16x16x16 PV mfma (m=l15=q, k=quad*4+r=key). V is pre-transposed in global.
__global__ __launch_bounds__(256, 4) void attn_kernel(
    const f16* __restrict__ Q, const f16* __restrict__ K_, const f16* __restrict__ VT,
    const float* __restrict__ btab, f16* __restrict__ O) {
  __shared__ float bias_lds[2112];   // read-only after init; conflict-free access pattern

  int qt = blockIdx.x, bh = blockIdx.y;
  int qbase = qt * 64;
  int h = bh & 15, b = bh >> 4;
  int tid = threadIdx.x, lane = tid & 63, wave = tid >> 6;
  int l15 = lane & 15, quad = lane >> 4;

  // stage per-head bias row (log2e pre-scaled)
  const float* brow = btab + h * 4095 + (1984 - qbase);
  for (int i = tid; i < 2111; i += 256) bias_lds[i] = brow[i];

  // Q fragments (B-operand of S^T mfma): B[n=q(l15)][k=d]
  const f16* qptr = Q + ((size_t)bh * 2048 + qbase + wave * 16 + l15) * 64 + quad * 8;
  f16x8 qf0 = *(const f16x8*)(qptr);
  f16x8 qf1 = *(const f16x8*)(qptr + 32);

  f32x4 accO[4] = {};                // O[q=quad*4+r][d=dblk*16+l15]
  float m_i = -INFINITY, l_i = 0.f;  // per-lane state for q = l15 (log2 space)

  const f16* kbp = K_ + (size_t)bh * 2048 * 64;
  const f16* vtp = VT + (size_t)bh * 64 * 2048;
  // bias index: key - q + offset;  key = kb + c*16 + quad*4 + r, q_local = wave*16 + l15
  const int bofs = quad * 4 - wave * 16 - l15 + 63;

  __syncthreads();

  for (int kt = 0; kt < 32; kt++) {
    int kb = kt * 64;
    // S^T tile: 64 keys x 16 q per wave, bias as accumulator init
    f32x4 scT[4];
#pragma unroll
    for (int c = 0; c < 4; c++) {
      int bi = kb + c * 16 + bofs;
      scT[c] = f32x4{ bias_lds[bi], bias_lds[bi + 1], bias_lds[bi + 2], bias_lds[bi + 3] };
      f16x8 kf0 = *(const f16x8*)(kbp + (size_t)(kb + c * 16 + l15) * 64 + quad * 8);
      f16x8 kf1 = *(const f16x8*)(kbp + (size_t)(kb + c * 16 + l15) * 64 + 32 + quad * 8);
      scT[c] = mfma16x32(kf0, qf0, scT[c]);
      scT[c] = mfma16x32(kf1, qf1, scT[c]);
    }
    // online softmax in log2 space; column q = l15, 16 elems in-lane + quads
    float mx = m_i;
#pragma unroll
    for (int c = 0; c < 4; c++)
#pragma unroll
      for (int r = 0; r < 4; r++) mx = fmaxf(mx, scT[c][r]);
    mx = fmaxf(mx, __shfl_xor(mx, 16));
    mx = fmaxf(mx, __shfl_xor(mx, 32));
    float alpha = exp2f(m_i - mx);
    m_i = mx;
    float rs = 0.f;
    f16x4 p[4];
#pragma unroll
    for (int c = 0; c < 4; c++) {
#pragma unroll
      for (int r = 0; r < 4; r++) {
        float e = exp2f(scT[c][r] - mx);
        rs += e;
        p[c][r] = (f16)e;
      }
    }
    rs += __shfl_xor(rs, 16);
    rs += __shfl_xor(rs, 32);
    l_i = l_i * alpha + rs;
    // rescale accO rows (q' = quad*4+r); alpha for q' lives in lane q' (0..15)
    float arow[4];
#pragma unroll
    for (int r = 0; r < 4; r++) arow[r] = __shfl(alpha, quad * 4 + r);
#pragma unroll
    for (int d = 0; d < 4; d++)
#pragma unroll
      for (int r = 0; r < 4; r++) accO[d][r] *= arow[r];
    // PV: accO[dblk] += P (A-frag, reinterpreted scT) x VT (B-frag, contiguous global)
#pragma unroll
    for (int c = 0; c < 4; c++) {
#pragma unroll
      for (int dblk = 0; dblk < 4; dblk++) {
        f16x4 vf = *(const f16x4*)(vtp + (size_t)(dblk * 16 + l15) * 2048 + kb + c * 16 + quad * 4);
        accO[dblk] = mfma16x16(p[c], vf, accO[dblk]);
      }
    }
    __syncthreads();  // no LDS hazard; keeps waves together for L1 K/V reuse
  }

  // epilogue: O[q][d] / l  -> Ow[b][s][h*64+d]
  float linv = 1.0f / l_i;
  float lrow[4];
#pragma unroll
  for (int r = 0; r < 4; r++) lrow[r] = __shfl(linv, quad * 4 + r);
#pragma unroll
  for (int dblk = 0; dblk < 4; dblk++) {
#pragma unroll
    for (int r = 0; r < 4; r++) {
      int q = qbase + wave * 16 + quad * 4 + r;
      O[((size_t)(b * 2048 + q) << 10) + h * 64 + dblk * 16 + l15] = (f16)(accO[dblk][r] * lrow[r]);
    }
  }
}

// ------------- GEMM2: out = Ow @ Wout_t^T (fp32 out) -------------
__global__ __launch_bounds__(256, 2) void gemm_out_kernel(
    const f16* __restrict__ Oh, const f16* __restrict__ Wt, float* __restrict__ out) {
  f32x4 acc[4][4];
  int m0 = blockIdx.y * 128, n0 = blockIdx.x * 128;
  gemm_core(Oh, Wt, m0, n0, 1024, acc);

  int lane = threadIdx.x & 63, wave = threadIdx.x >> 6;
  int l15 = lane & 15, quad = lane >> 4;
  int wr = (wave >> 1) * 64, wc = (wave & 1) * 64;
#pragma unroll
  for (int i = 0; i < 4; i++) {
#pragma unroll
    for (int j = 0; j < 4; j++) {
      int n = n0 + wc + j * 16 + l15;
#pragma unroll
      for (int r = 0; r < 4; r++) {
        int m = m0 + wr + i * 16 + quad * 4 + r;
        out[((size_t)m << 10) + n] = acc[i][j][r];
      }
    }
  }
}

extern "C" void kernel_launch(void* const* d_in, const int* in_sizes, int n_in,
                              void* d_out, int out_size, void* d_ws, size_t ws_size,
                              hipStream_t stream) {
  const float* X = (const float*)d_in[0];     // (2,2048,1024)
  const float* Wqkv = (const float*)d_in[1];  // (1024,3072)
  const float* Wout = (const float*)d_in[2];  // (1024,1024)
  const float* rel = (const float*)d_in[3];   // (32,16)

  char* ws = (char*)d_ws;
  f16* Xh     = (f16*)(ws + 0);
  f16* Wqkv_t = (f16*)(ws + 8388608);
  f16* Wout_t = (f16*)(ws + 14680064);
  f16* Qw     = (f16*)(ws + 16777216);
  f16* Kw     = (f16*)(ws + 25165824);
  f16* VTw    = (f16*)(ws + 33554432);
  f16* Ow     = (f16*)(ws + 41943040);
  float* btab = (float*)(ws + 50331648);

  cast_x_kernel<<<4096, 256, 0, stream>>>(X, Xh);
  transpose_cast_kernel<<<dim3(96, 32), 256, 0, stream>>>(Wqkv, Wqkv_t, 1024, 3072);
  transpose_cast_kernel<<<dim3(32, 32), 256, 0, stream>>>(Wout, Wout_t, 1024, 1024);
  bias_table_kernel<<<16, 256, 0, stream>>>(rel, btab);
  gemm_qkv_kernel<<<dim3(24, 32), 256, 0, stream>>>(Xh, Wqkv_t, Qw, Kw, VTw);
  attn_kernel<<<dim3(32, 32), 256, 0, stream>>>(Qw, Kw, VTw, btab, Ow);
  gemm_out_kernel<<<dim3(8, 32), 256, 0, stream>>>(Ow, Wout_t, (float*)d_out);
}

// Round 4
// 256.095 us; speedup vs baseline: 1.9012x; 1.9012x over previous
//
#include <hip/hip_runtime.h>
#include <hip/hip_bf16.h>
#include <math.h>

typedef _Float16 f16;
typedef __attribute__((ext_vector_type(8))) _Float16 f16x8;
typedef __attribute__((ext_vector_type(4))) _Float16 f16x4;
typedef __attribute__((ext_vector_type(4))) float f32x4;

#define EMBED 1024
#define NHEADS 16
#define HDIM 64
#define BATCH 2
#define SEQ 2048
#define BS 4096  // BATCH*SEQ
#define LOG2E 1.4426950408889634f

// ---------------- ws layout (bytes) ----------------
// Xh:      0         (BS*EMBED f16 = 8388608)   -- consumed by gemm_qkv, then
// Kp:      0         ALIASES Xh (8388608 B)     -- written by repack_k afterwards
// Wqkv_t:  8388608   (3072*1024 f16 = 6291456)
// Wout_t:  14680064  (1024*1024 f16 = 2097152)
// Qw:      16777216  [bh][s][d], pre-scaled by log2e
// Kw:      25165824  [bh][s][d] raw
// Vp:      33554432  fragment-packed: [bh][kt32][c4][dblk4][lane64][4] f16
// Ow:      41943040  ([B][S][H*64] f16)
// btab:    50331648  (16*4095 f32, pre-scaled by log2e)
// total ~50.6 MB (same as the proven round-2 footprint)

__device__ __forceinline__ f32x4 mfma16x32(f16x8 a, f16x8 b, f32x4 c) {
  return __builtin_amdgcn_mfma_f32_16x16x32_f16(a, b, c, 0, 0, 0);
}
__device__ __forceinline__ f32x4 mfma16x16(f16x4 a, f16x4 b, f32x4 c) {
  return __builtin_amdgcn_mfma_f32_16x16x16f16(a, b, c, 0, 0, 0);
}

// ---------------- cast fp32 -> fp16 ----------------
__global__ void cast_x_kernel(const float* __restrict__ src, f16* __restrict__ dst) {
  int i = (blockIdx.x * 256 + threadIdx.x) * 4;
  float4 v = *(const float4*)(src + i);
  f16x4 o = { (f16)v.x, (f16)v.y, (f16)v.z, (f16)v.w };
  *(f16x4*)(dst + i) = o;
}

// ------------- transpose + cast: in[K][N] fp32 -> out[N][K] fp16 -------------
__global__ void transpose_cast_kernel(const float* __restrict__ in, f16* __restrict__ out,
                                      int K, int N) {
  __shared__ float tile[32][33];
  int n0 = blockIdx.x * 32, k0 = blockIdx.y * 32;
  int tx = threadIdx.x & 31, ty = threadIdx.x >> 5;  // 256 thr: ty 0..7
#pragma unroll
  for (int r = ty; r < 32; r += 8) tile[r][tx] = in[(size_t)(k0 + r) * N + n0 + tx];
  __syncthreads();
#pragma unroll
  for (int r = ty; r < 32; r += 8) out[(size_t)(n0 + r) * K + k0 + tx] = (f16)tile[tx][r];
}

// ------------- relative-position bias table: btab[h][rp+2047], scaled by log2e -------------
__global__ void bias_table_kernel(const float* __restrict__ rel_emb, float* __restrict__ btab) {
  int idx = blockIdx.x * 256 + threadIdx.x;  // 0..4094
  if (idx >= 4095) return;
  int rp = idx - 2047;                       // rp = k - q
  int rb = rp > 0 ? 16 : 0;
  int arp = rp < 0 ? -rp : rp;
  int loc;
  if (arp < 8) {
    loc = arp;
  } else {
    float lr = logf((float)arp * 0.125f) * (1.0f / 2.7725887222397811f);
    int t = 8 + (int)(lr * 8.0f);
    loc = t < 15 ? t : 15;
  }
  int bucket = rb + loc;
#pragma unroll
  for (int h = 0; h < 16; h++) btab[h * 4095 + idx] = rel_emb[bucket * 16 + h] * LOG2E;
}

// ------------- shared GEMM core: C[128x128] = A[MxK] * Bt[NxK]^T -------------
__device__ __forceinline__ void gemm_core(const f16* __restrict__ A, const f16* __restrict__ Bt,
                                          int m0, int n0, int Kdim, f32x4 (&acc)[4][4]) {
  __shared__ __align__(16) f16 As[128 * 40];  // [m][k] stride 40
  __shared__ __align__(16) f16 Bs[128 * 40];  // [n][k] stride 40

  int tid = threadIdx.x;
  int lane = tid & 63, wave = tid >> 6;
  int l15 = lane & 15, quad = lane >> 4;
  int wr = (wave >> 1) * 64, wc = (wave & 1) * 64;

#pragma unroll
  for (int i = 0; i < 4; i++)
#pragma unroll
    for (int j = 0; j < 4; j++) acc[i][j] = f32x4{0.f, 0.f, 0.f, 0.f};

  for (int kt = 0; kt < Kdim / 32; kt++) {
    int kk = kt * 32;
#pragma unroll
    for (int c = 0; c < 2; c++) {
      int i = c * 256 + tid;            // 0..511 chunks of 8 f16
      int row = i >> 2, cc = (i & 3) * 8;
      int4 av = *(const int4*)(A + (size_t)(m0 + row) * Kdim + kk + cc);
      int4 bv = *(const int4*)(Bt + (size_t)(n0 + row) * Kdim + kk + cc);
      *(int4*)(&As[row * 40 + cc]) = av;
      *(int4*)(&Bs[row * 40 + cc]) = bv;
    }
    __syncthreads();
    f16x8 af[4], bf[4];
#pragma unroll
    for (int i = 0; i < 4; i++) af[i] = *(const f16x8*)(&As[(wr + i * 16 + l15) * 40 + quad * 8]);
#pragma unroll
    for (int j = 0; j < 4; j++) bf[j] = *(const f16x8*)(&Bs[(wc + j * 16 + l15) * 40 + quad * 8]);
#pragma unroll
    for (int i = 0; i < 4; i++)
#pragma unroll
      for (int j = 0; j < 4; j++) acc[i][j] = mfma16x32(af[i], bf[j], acc[i][j]);
    __syncthreads();
  }
}

// ------------- GEMM1: qkv = Xh @ Wqkv_t^T; Q scaled by log2e; V fragment-packed -------------
__global__ __launch_bounds__(256, 2) void gemm_qkv_kernel(
    const f16* __restrict__ Xh, const f16* __restrict__ Wt,
    f16* __restrict__ Q, f16* __restrict__ K_, f16* __restrict__ Vp) {
  f32x4 acc[4][4];
  int m0 = blockIdx.y * 128, n0 = blockIdx.x * 128;
  gemm_core(Xh, Wt, m0, n0, 1024, acc);

  int lane = threadIdx.x & 63, wave = threadIdx.x >> 6;
  int l15 = lane & 15, quad = lane >> 4;
  int wr = (wave >> 1) * 64, wc = (wave & 1) * 64;
  int nq = n0 + wc;          // 64-aligned; uniform per wave quadrant
  int which = nq >> 10;
  int h = (nq >> 6) & 15;
  int b = m0 >> 11;          // 128-tile never crosses batch boundary

  if (which == 2) {
    // Vp[bh][kt][c=i][dblk=j][lane][4], element (d=j*16+l15, s=kt*64+i*16+quad*4+r)
    int s0 = (m0 & 2047) + wr;  // 64-aligned
    f16* vbase = Vp + (size_t)(b * 16 + h) * 131072 + (size_t)(s0 >> 6) * 4096;
#pragma unroll
    for (int i = 0; i < 4; i++) {
#pragma unroll
      for (int j = 0; j < 4; j++) {
        f16x4 pk = { (f16)acc[i][j][0], (f16)acc[i][j][1], (f16)acc[i][j][2], (f16)acc[i][j][3] };
        *(f16x4*)(vbase + (i * 4 + j) * 256 + lane * 4) = pk;
      }
    }
  } else {
    f16* base = (which == 0) ? Q : K_;
    float sc = (which == 0) ? LOG2E : 1.0f;
#pragma unroll
    for (int i = 0; i < 4; i++) {
#pragma unroll
      for (int j = 0; j < 4; j++) {
        int d = j * 16 + l15;
#pragma unroll
        for (int r = 0; r < 4; r++) {
          int m = m0 + wr + i * 16 + quad * 4 + r;
          int s = m & 2047;
          base[(((size_t)(b * 16 + h) * 2048 + s) << 6) + d] = (f16)(acc[i][j][r] * sc);
        }
      }
    }
  }
}

// ------------- repack K into fragment order: Kp[bh][kt][c][t][lane][8] -------------
// element (s = kt*64 + c*16 + (lane&15), d = t*32 + (lane>>4)*8 + j)
// per-(c,t) slot = 64 lanes * 8 f16 = 512 f16  <-- element stride, not bytes!
__global__ void repack_k_kernel(const f16* __restrict__ Kw, f16* __restrict__ Kp) {
  int o = blockIdx.x * 256 + threadIdx.x;   // out-chunk index, 524288 total
  int lane = o & 63;
  int ct = (o >> 6) & 7;                    // c*2 + t
  int kt = (o >> 9) & 31;
  int bh = o >> 14;
  int c = ct >> 1, t = ct & 1;
  int l15 = lane & 15, quad = lane >> 4;
  int s = kt * 64 + c * 16 + l15;
  f16x8 v = *(const f16x8*)(Kw + ((size_t)(bh * 2048 + s) << 6) + t * 32 + quad * 8);
  *(f16x8*)(Kp + (size_t)o * 8) = v;        // perfectly coalesced write
}

// ------------- flash attention: all hot-loop loads lane-contiguous -------------
// S^T per tile: mfma(kf,qf) -> C[key][q]; C-frag of S^T == A-frag of P for 16x16x16 PV.
__global__ __launch_bounds__(256, 4) void attn_kernel(
    const f16* __restrict__ Q, const f16* __restrict__ Kp, const f16* __restrict__ Vp,
    const float* __restrict__ btab, f16* __restrict__ O) {
  __shared__ float bias_lds[2112];

  int qt = blockIdx.x, bh = blockIdx.y;
  int qbase = qt * 64;
  int h = bh & 15, b = bh >> 4;
  int tid = threadIdx.x, lane = tid & 63, wave = tid >> 6;
  int l15 = lane & 15, quad = lane >> 4;

  const float* brow = btab + h * 4095 + (1984 - qbase);
  for (int i = tid; i < 2111; i += 256) bias_lds[i] = brow[i];

  // Q fragments (B-operand of S^T mfma): B[n=q(l15)][k=d]
  const f16* qptr = Q + ((size_t)bh * 2048 + qbase + wave * 16 + l15) * 64 + quad * 8;
  f16x8 qf0 = *(const f16x8*)(qptr);
  f16x8 qf1 = *(const f16x8*)(qptr + 32);

  f32x4 accO[4] = {};                // O[q=quad*4+r][d=dblk*16+l15]
  float m_i = -INFINITY, l_i = 0.f;  // per-lane state for q = l15 (log2 space)

  const f16* kpp = Kp + (size_t)bh * 131072;
  const f16* vpp = Vp + (size_t)bh * 131072;
  const int bofs = quad * 4 - wave * 16 - l15 + 63;

  __syncthreads();

  for (int kt = 0; kt < 32; kt++) {
    const f16* kptr = kpp + kt * 4096;
    const f16* vptr = vpp + kt * 4096;
    int kb = kt * 64;
    // S^T tile: 64 keys x 16 q per wave, bias as accumulator init
    f32x4 scT[4];
#pragma unroll
    for (int c = 0; c < 4; c++) {
      int bi = kb + c * 16 + bofs;
      scT[c] = f32x4{ bias_lds[bi], bias_lds[bi + 1], bias_lds[bi + 2], bias_lds[bi + 3] };
      f16x8 kf0 = *(const f16x8*)(kptr + (c * 2 + 0) * 512 + lane * 8);
      f16x8 kf1 = *(const f16x8*)(kptr + (c * 2 + 1) * 512 + lane * 8);
      scT[c] = mfma16x32(kf0, qf0, scT[c]);
      scT[c] = mfma16x32(kf1, qf1, scT[c]);
    }
    // V fragments early so vmcnt overlaps the softmax VALU work
    f16x4 vf[4][4];
#pragma unroll
    for (int c = 0; c < 4; c++)
#pragma unroll
      for (int dblk = 0; dblk < 4; dblk++)
        vf[c][dblk] = *(const f16x4*)(vptr + (c * 4 + dblk) * 256 + lane * 4);
    // online softmax in log2 space; column q = l15
    float mx = m_i;
#pragma unroll
    for (int c = 0; c < 4; c++)
#pragma unroll
      for (int r = 0; r < 4; r++) mx = fmaxf(mx, scT[c][r]);
    mx = fmaxf(mx, __shfl_xor(mx, 16));
    mx = fmaxf(mx, __shfl_xor(mx, 32));
    float alpha = exp2f(m_i - mx);
    m_i = mx;
    float rs = 0.f;
    f16x4 p[4];
#pragma unroll
    for (int c = 0; c < 4; c++) {
#pragma unroll
      for (int r = 0; r < 4; r++) {
        float e = exp2f(scT[c][r] - mx);
        rs += e;
        p[c][r] = (f16)e;
      }
    }
    rs += __shfl_xor(rs, 16);
    rs += __shfl_xor(rs, 32);
    l_i = l_i * alpha + rs;
    float arow[4];
#pragma unroll
    for (int r = 0; r < 4; r++) arow[r] = __shfl(alpha, quad * 4 + r);
#pragma unroll
    for (int d = 0; d < 4; d++)
#pragma unroll
      for (int r = 0; r < 4; r++) accO[d][r] *= arow[r];
    // PV: accO[dblk] += P (A-frag = reinterpreted scT) x V (fragment-packed)
#pragma unroll
    for (int c = 0; c < 4; c++)
#pragma unroll
      for (int dblk = 0; dblk < 4; dblk++)
        accO[dblk] = mfma16x16(p[c], vf[c][dblk], accO[dblk]);
  }

  // epilogue: O[q][d] / l  -> Ow[b][s][h*64+d]
  float linv = 1.0f / l_i;
  float lrow[4];
#pragma unroll
  for (int r = 0; r < 4; r++) lrow[r] = __shfl(linv, quad * 4 + r);
#pragma unroll
  for (int dblk = 0; dblk < 4; dblk++) {
#pragma unroll
    for (int r = 0; r < 4; r++) {
      int q = qbase + wave * 16 + quad * 4 + r;
      O[((size_t)(b * 2048 + q) << 10) + h * 64 + dblk * 16 + l15] = (f16)(accO[dblk][r] * lrow[r]);
    }
  }
}

// ------------- GEMM2: out = Ow @ Wout_t^T (fp32 out) -------------
__global__ __launch_bounds__(256, 2) void gemm_out_kernel(
    const f16* __restrict__ Oh, const f16* __restrict__ Wt, float* __restrict__ out) {
  f32x4 acc[4][4];
  int m0 = blockIdx.y * 128, n0 = blockIdx.x * 128;
  gemm_core(Oh, Wt, m0, n0, 1024, acc);

  int lane = threadIdx.x & 63, wave = threadIdx.x >> 6;
  int l15 = lane & 15, quad = lane >> 4;
  int wr = (wave >> 1) * 64, wc = (wave & 1) * 64;
#pragma unroll
  for (int i = 0; i < 4; i++) {
#pragma unroll
    for (int j = 0; j < 4; j++) {
      int n = n0 + wc + j * 16 + l15;
#pragma unroll
      for (int r = 0; r < 4; r++) {
        int m = m0 + wr + i * 16 + quad * 4 + r;
        out[((size_t)m << 10) + n] = acc[i][j][r];
      }
    }
  }
}

extern "C" void kernel_launch(void* const* d_in, const int* in_sizes, int n_in,
                              void* d_out, int out_size, void* d_ws, size_t ws_size,
                              hipStream_t stream) {
  const float* X = (const float*)d_in[0];     // (2,2048,1024)
  const float* Wqkv = (const float*)d_in[1];  // (1024,3072)
  const float* Wout = (const float*)d_in[2];  // (1024,1024)
  const float* rel = (const float*)d_in[3];   // (32,16)

  char* ws = (char*)d_ws;
  f16* Xh     = (f16*)(ws + 0);
  f16* Kp     = (f16*)(ws + 0);         // aliases Xh; written after Xh's last read
  f16* Wqkv_t = (f16*)(ws + 8388608);
  f16* Wout_t = (f16*)(ws + 14680064);
  f16* Qw     = (f16*)(ws + 16777216);
  f16* Kw     = (f16*)(ws + 25165824);
  f16* Vp     = (f16*)(ws + 33554432);
  f16* Ow     = (f16*)(ws + 41943040);
  float* btab = (float*)(ws + 50331648);

  cast_x_kernel<<<4096, 256, 0, stream>>>(X, Xh);
  transpose_cast_kernel<<<dim3(96, 32), 256, 0, stream>>>(Wqkv, Wqkv_t, 1024, 3072);
  transpose_cast_kernel<<<dim3(32, 32), 256, 0, stream>>>(Wout, Wout_t, 1024, 1024);
  bias_table_kernel<<<16, 256, 0, stream>>>(rel, btab);
  gemm_qkv_kernel<<<dim3(24, 32), 256, 0, stream>>>(Xh, Wqkv_t, Qw, Kw, Vp);
  repack_k_kernel<<<2048, 256, 0, stream>>>(Kw, Kp);
  attn_kernel<<<dim3(32, 32), 256, 0, stream>>>(Qw, Kp, Vp, btab, Ow);
  gemm_out_kernel<<<dim3(8, 32), 256, 0, stream>>>(Ow, Wout_t, (float*)d_out);
}

// Round 5
// 234.316 us; speedup vs baseline: 2.0779x; 1.0929x over previous
//
#include <hip/hip_runtime.h>
#include <hip/hip_bf16.h>
#include <math.h>

typedef _Float16 f16;
typedef __attribute__((ext_vector_type(8))) _Float16 f16x8;
typedef __attribute__((ext_vector_type(4))) _Float16 f16x4;
typedef __attribute__((ext_vector_type(4))) float f32x4;

#define EMBED 1024
#define NHEADS 16
#define HDIM 64
#define BATCH 2
#define SEQ 2048
#define BS 4096  // BATCH*SEQ
#define LOG2E 1.4426950408889634f

// ---------------- ws layout (bytes) ----------------
// Xh:      0         (BS*EMBED f16 = 8388608)   -- consumed by gemm_qkv, then
// Kp:      0         ALIASES Xh (8388608 B)     -- written by repack_k afterwards
// Wqkv_t:  8388608   (3072*1024 f16 = 6291456)
// Wout_t:  14680064  (1024*1024 f16 = 2097152)
// Qw:      16777216  [bh][s][d], pre-scaled by log2e
// Kw:      25165824  [bh][s][d] raw
// Vp:      33554432  fragment-packed: [bh][kt32][c4][jp2][lane64][8] f16
// Ow:      41943040  ([B][S][H*64] f16)
// btab:    50331648  (16*4095 f32, pre-scaled by log2e)
// total ~50.6 MB (proven footprint)

__device__ __forceinline__ f32x4 mfma16x32(f16x8 a, f16x8 b, f32x4 c) {
  return __builtin_amdgcn_mfma_f32_16x16x32_f16(a, b, c, 0, 0, 0);
}
__device__ __forceinline__ f32x4 mfma16x16(f16x4 a, f16x4 b, f32x4 c) {
  return __builtin_amdgcn_mfma_f32_16x16x16f16(a, b, c, 0, 0, 0);
}
// async global->LDS, 16 B per lane; LDS dest = wave-uniform base + lane*16
__device__ __forceinline__ void gload_lds16(const f16* __restrict__ g, f16* l) {
  __builtin_amdgcn_global_load_lds(
      (const __attribute__((address_space(1))) void*)g,
      (__attribute__((address_space(3))) void*)l, 16, 0, 0);
}

// ---------------- cast fp32 -> fp16 ----------------
__global__ void cast_x_kernel(const float* __restrict__ src, f16* __restrict__ dst) {
  int i = (blockIdx.x * 256 + threadIdx.x) * 4;
  float4 v = *(const float4*)(src + i);
  f16x4 o = { (f16)v.x, (f16)v.y, (f16)v.z, (f16)v.w };
  *(f16x4*)(dst + i) = o;
}

// ------------- transpose + cast: in[K][N] fp32 -> out[N][K] fp16 -------------
__global__ void transpose_cast_kernel(const float* __restrict__ in, f16* __restrict__ out,
                                      int K, int N) {
  __shared__ float tile[32][33];
  int n0 = blockIdx.x * 32, k0 = blockIdx.y * 32;
  int tx = threadIdx.x & 31, ty = threadIdx.x >> 5;  // 256 thr: ty 0..7
#pragma unroll
  for (int r = ty; r < 32; r += 8) tile[r][tx] = in[(size_t)(k0 + r) * N + n0 + tx];
  __syncthreads();
#pragma unroll
  for (int r = ty; r < 32; r += 8) out[(size_t)(n0 + r) * K + k0 + tx] = (f16)tile[tx][r];
}

// ------------- relative-position bias table: btab[h][rp+2047], scaled by log2e -------------
__global__ void bias_table_kernel(const float* __restrict__ rel_emb, float* __restrict__ btab) {
  int idx = blockIdx.x * 256 + threadIdx.x;  // 0..4094
  if (idx >= 4095) return;
  int rp = idx - 2047;                       // rp = k - q
  int rb = rp > 0 ? 16 : 0;
  int arp = rp < 0 ? -rp : rp;
  int loc;
  if (arp < 8) {
    loc = arp;
  } else {
    float lr = logf((float)arp * 0.125f) * (1.0f / 2.7725887222397811f);
    int t = 8 + (int)(lr * 8.0f);
    loc = t < 15 ? t : 15;
  }
  int bucket = rb + loc;
#pragma unroll
  for (int h = 0; h < 16; h++) btab[h * 4095 + idx] = rel_emb[bucket * 16 + h] * LOG2E;
}

// ------------- shared GEMM core (m97-style): C[128x128] = A[MxK] * Bt[NxK]^T -------------
// global_load_lds width=16 staging into unpadded [row][32] LDS tiles.
__device__ __forceinline__ void gemm_core(const f16* __restrict__ A, const f16* __restrict__ Bt,
                                          int m0, int n0, int Kdim, f32x4 (&acc)[4][4]) {
  __shared__ __align__(16) f16 As[128 * 32];  // [m][k], 64 B rows, no pad
  __shared__ __align__(16) f16 Bs[128 * 32];  // [n][k]

  int tid = threadIdx.x;
  int lane = tid & 63, wave = tid >> 6;
  int l15 = lane & 15, quad = lane >> 4;
  int wr = (wave >> 1) * 64, wc = (wave & 1) * 64;
  int rowl = lane >> 2;          // 0..15: 4 lanes per 64-B row
  int col8 = (lane & 3) * 8;     // f16 offset of this lane's 16-B chunk

#pragma unroll
  for (int i = 0; i < 4; i++)
#pragma unroll
    for (int j = 0; j < 4; j++) acc[i][j] = f32x4{0.f, 0.f, 0.f, 0.f};

  for (int kt = 0; kt < Kdim / 32; kt++) {
    int kk = kt * 32;
    // stage: each wave loads 32 rows of A and 32 rows of B (2 instrs each)
#pragma unroll
    for (int c = 0; c < 2; c++) {
      int row = wave * 32 + c * 16 + rowl;
      gload_lds16(A + (size_t)(m0 + row) * Kdim + kk + col8, &As[(wave * 32 + c * 16) * 32]);
      gload_lds16(Bt + (size_t)(n0 + row) * Kdim + kk + col8, &Bs[(wave * 32 + c * 16) * 32]);
    }
    __syncthreads();
    f16x8 af[4], bf[4];
#pragma unroll
    for (int i = 0; i < 4; i++) af[i] = *(const f16x8*)(&As[(wr + i * 16 + l15) * 32 + quad * 8]);
#pragma unroll
    for (int j = 0; j < 4; j++) bf[j] = *(const f16x8*)(&Bs[(wc + j * 16 + l15) * 32 + quad * 8]);
#pragma unroll
    for (int i = 0; i < 4; i++)
#pragma unroll
      for (int j = 0; j < 4; j++) acc[i][j] = mfma16x32(af[i], bf[j], acc[i][j]);
    __syncthreads();
  }
}

// ------------- GEMM1: qkv = Xh @ Wqkv_t^T; Q scaled by log2e; V fragment-packed -------------
__global__ __launch_bounds__(256, 2) void gemm_qkv_kernel(
    const f16* __restrict__ Xh, const f16* __restrict__ Wt,
    f16* __restrict__ Q, f16* __restrict__ K_, f16* __restrict__ Vp) {
  f32x4 acc[4][4];
  int m0 = blockIdx.y * 128, n0 = blockIdx.x * 128;
  gemm_core(Xh, Wt, m0, n0, 1024, acc);

  int lane = threadIdx.x & 63, wave = threadIdx.x >> 6;
  int l15 = lane & 15, quad = lane >> 4;
  int wr = (wave >> 1) * 64, wc = (wave & 1) * 64;
  int nq = n0 + wc;          // 64-aligned; uniform per wave quadrant
  int which = nq >> 10;
  int h = (nq >> 6) & 15;
  int b = m0 >> 11;          // 128-tile never crosses batch boundary

  if (which == 2) {
    // Vp[bh][kt][c=i][jp][lane][8]: elements (d=(2jp+half)*16+l15, s=..i*16+quad*4+r)
    int s0 = (m0 & 2047) + wr;  // 64-aligned
    f16* vbase = Vp + (size_t)(b * 16 + h) * 131072 + (size_t)(s0 >> 6) * 4096;
#pragma unroll
    for (int i = 0; i < 4; i++) {
#pragma unroll
      for (int jp = 0; jp < 2; jp++) {
        f16x8 pk = { (f16)acc[i][2 * jp][0],     (f16)acc[i][2 * jp][1],
                     (f16)acc[i][2 * jp][2],     (f16)acc[i][2 * jp][3],
                     (f16)acc[i][2 * jp + 1][0], (f16)acc[i][2 * jp + 1][1],
                     (f16)acc[i][2 * jp + 1][2], (f16)acc[i][2 * jp + 1][3] };
        *(f16x8*)(vbase + (i * 2 + jp) * 512 + lane * 8) = pk;
      }
    }
  } else {
    f16* base = (which == 0) ? Q : K_;
    float sc = (which == 0) ? LOG2E : 1.0f;
#pragma unroll
    for (int i = 0; i < 4; i++) {
#pragma unroll
      for (int j = 0; j < 4; j++) {
        int d = j * 16 + l15;
#pragma unroll
        for (int r = 0; r < 4; r++) {
          int m = m0 + wr + i * 16 + quad * 4 + r;
          int s = m & 2047;
          base[(((size_t)(b * 16 + h) * 2048 + s) << 6) + d] = (f16)(acc[i][j][r] * sc);
        }
      }
    }
  }
}

// ------------- repack K into fragment order: Kp[bh][kt][c][t][lane][8] -------------
// element (s = kt*64 + c*16 + (lane&15), d = t*32 + (lane>>4)*8 + j); slot stride 512 f16
__global__ void repack_k_kernel(const f16* __restrict__ Kw, f16* __restrict__ Kp) {
  int o = blockIdx.x * 256 + threadIdx.x;   // out-chunk index, 524288 total
  int lane = o & 63;
  int ct = (o >> 6) & 7;                    // c*2 + t
  int kt = (o >> 9) & 31;
  int bh = o >> 14;
  int c = ct >> 1, t = ct & 1;
  int l15 = lane & 15, quad = lane >> 4;
  int s = kt * 64 + c * 16 + l15;
  f16x8 v = *(const f16x8*)(Kw + ((size_t)(bh * 2048 + s) << 6) + t * 32 + quad * 8);
  *(f16x8*)(Kp + (size_t)o * 8) = v;        // perfectly coalesced write
}

// ------------- flash attention: all hot-loop loads lane-contiguous -------------
// S^T per tile: mfma(kf,qf) -> C[key][q]; C-frag of S^T == A-frag of P for 16x16x16 PV.
__global__ __launch_bounds__(256, 4) void attn_kernel(
    const f16* __restrict__ Q, const f16* __restrict__ Kp, const f16* __restrict__ Vp,
    const float* __restrict__ btab, f16* __restrict__ O) {
  // 4 shift-aligned copies: bias4[j][i] = brow[i+j] -> any [bi..bi+3] is one aligned b128
  __shared__ __align__(16) float bias4[4][2116];

  int qt = blockIdx.x, bh = blockIdx.y;
  int qbase = qt * 64;
  int h = bh & 15, b = bh >> 4;
  int tid = threadIdx.x, lane = tid & 63, wave = tid >> 6;
  int l15 = lane & 15, quad = lane >> 4;

  const float* brow = btab + h * 4095 + (1984 - qbase);
#pragma unroll
  for (int j = 0; j < 4; j++)
    for (int i = tid; i < 2116; i += 256) {
      int src = i + j;
      bias4[j][i] = (src <= 2110) ? brow[src] : 0.f;
    }

  // Q fragments (B-operand of S^T mfma): B[n=q(l15)][k=d]
  const f16* qptr = Q + ((size_t)bh * 2048 + qbase + wave * 16 + l15) * 64 + quad * 8;
  f16x8 qf0 = *(const f16x8*)(qptr);
  f16x8 qf1 = *(const f16x8*)(qptr + 32);

  f32x4 accO[4] = {};                // O[q=quad*4+r][d=dblk*16+l15]
  float m_i = -INFINITY, l_i = 0.f;  // per-lane state for q = l15 (log2 space)

  const f16* kpp = Kp + (size_t)bh * 131072;
  const f16* vpp = Vp + (size_t)bh * 131072;
  const int bofs = quad * 4 - wave * 16 - l15 + 63;

  __syncthreads();

  for (int kt = 0; kt < 32; kt++) {
    const f16* kptr = kpp + kt * 4096;
    const f16* vptr = vpp + kt * 4096;
    int kb = kt * 64;
    // S^T tile: 64 keys x 16 q per wave, bias (aligned b128 read) as accumulator init
    f32x4 scT[4];
#pragma unroll
    for (int c = 0; c < 4; c++) {
      int bi = kb + c * 16 + bofs;
      int bj = bi & 3;
      scT[c] = *(const f32x4*)(&bias4[bj][bi - bj]);
      f16x8 kf0 = *(const f16x8*)(kptr + (c * 2 + 0) * 512 + lane * 8);
      f16x8 kf1 = *(const f16x8*)(kptr + (c * 2 + 1) * 512 + lane * 8);
      scT[c] = mfma16x32(kf0, qf0, scT[c]);
      scT[c] = mfma16x32(kf1, qf1, scT[c]);
    }
    // V fragments (paired dblk -> dwordx4) early so vmcnt overlaps softmax VALU
    f16x8 vf8[4][2];
#pragma unroll
    for (int c = 0; c < 4; c++)
#pragma unroll
      for (int jp = 0; jp < 2; jp++)
        vf8[c][jp] = *(const f16x8*)(vptr + (c * 2 + jp) * 512 + lane * 8);
    // online softmax in log2 space; column q = l15; pairwise trees
    float mc[4];
#pragma unroll
    for (int c = 0; c < 4; c++)
      mc[c] = fmaxf(fmaxf(scT[c][0], scT[c][1]), fmaxf(scT[c][2], scT[c][3]));
    float mx = fmaxf(fmaxf(fmaxf(mc[0], mc[1]), fmaxf(mc[2], mc[3])), m_i);
    mx = fmaxf(mx, __shfl_xor(mx, 16));
    mx = fmaxf(mx, __shfl_xor(mx, 32));
    float alpha = exp2f(m_i - mx);
    m_i = mx;
    f16x4 p[4];
    float rc[4];
#pragma unroll
    for (int c = 0; c < 4; c++) {
      float e0 = exp2f(scT[c][0] - mx);
      float e1 = exp2f(scT[c][1] - mx);
      float e2 = exp2f(scT[c][2] - mx);
      float e3 = exp2f(scT[c][3] - mx);
      rc[c] = (e0 + e1) + (e2 + e3);
      p[c][0] = (f16)e0; p[c][1] = (f16)e1; p[c][2] = (f16)e2; p[c][3] = (f16)e3;
    }
    float rs = (rc[0] + rc[1]) + (rc[2] + rc[3]);
    rs += __shfl_xor(rs, 16);
    rs += __shfl_xor(rs, 32);
    l_i = l_i * alpha + rs;
    float arow[4];
#pragma unroll
    for (int r = 0; r < 4; r++) arow[r] = __shfl(alpha, quad * 4 + r);
#pragma unroll
    for (int d = 0; d < 4; d++)
#pragma unroll
      for (int r = 0; r < 4; r++) accO[d][r] *= arow[r];
    // PV: accO[dblk] += P (A-frag = reinterpreted scT) x V (fragment-packed)
#pragma unroll
    for (int c = 0; c < 4; c++) {
#pragma unroll
      for (int jp = 0; jp < 2; jp++) {
        f16x4 vlo = __builtin_shufflevector(vf8[c][jp], vf8[c][jp], 0, 1, 2, 3);
        f16x4 vhi = __builtin_shufflevector(vf8[c][jp], vf8[c][jp], 4, 5, 6, 7);
        accO[2 * jp]     = mfma16x16(p[c], vlo, accO[2 * jp]);
        accO[2 * jp + 1] = mfma16x16(p[c], vhi, accO[2 * jp + 1]);
      }
    }
  }

  // epilogue: O[q][d] / l  -> Ow[b][s][h*64+d]
  float linv = 1.0f / l_i;
  float lrow[4];
#pragma unroll
  for (int r = 0; r < 4; r++) lrow[r] = __shfl(linv, quad * 4 + r);
#pragma unroll
  for (int dblk = 0; dblk < 4; dblk++) {
#pragma unroll
    for (int r = 0; r < 4; r++) {
      int q = qbase + wave * 16 + quad * 4 + r;
      O[((size_t)(b * 2048 + q) << 10) + h * 64 + dblk * 16 + l15] = (f16)(accO[dblk][r] * lrow[r]);
    }
  }
}

// ------------- GEMM2: out = Ow @ Wout_t^T (fp32 out) -------------
__global__ __launch_bounds__(256, 2) void gemm_out_kernel(
    const f16* __restrict__ Oh, const f16* __restrict__ Wt, float* __restrict__ out) {
  f32x4 acc[4][4];
  int m0 = blockIdx.y * 128, n0 = blockIdx.x * 128;
  gemm_core(Oh, Wt, m0, n0, 1024, acc);

  int lane = threadIdx.x & 63, wave = threadIdx.x >> 6;
  int l15 = lane & 15, quad = lane >> 4;
  int wr = (wave >> 1) * 64, wc = (wave & 1) * 64;
#pragma unroll
  for (int i = 0; i < 4; i++) {
#pragma unroll
    for (int j = 0; j < 4; j++) {
      int n = n0 + wc + j * 16 + l15;
#pragma unroll
      for (int r = 0; r < 4; r++) {
        int m = m0 + wr + i * 16 + quad * 4 + r;
        out[((size_t)m << 10) + n] = acc[i][j][r];
      }
    }
  }
}

extern "C" void kernel_launch(void* const* d_in, const int* in_sizes, int n_in,
                              void* d_out, int out_size, void* d_ws, size_t ws_size,
                              hipStream_t stream) {
  const float* X = (const float*)d_in[0];     // (2,2048,1024)
  const float* Wqkv = (const float*)d_in[1];  // (1024,3072)
  const float* Wout = (const float*)d_in[2];  // (1024,1024)
  const float* rel = (const float*)d_in[3];   // (32,16)

  char* ws = (char*)d_ws;
  f16* Xh     = (f16*)(ws + 0);
  f16* Kp     = (f16*)(ws + 0);         // aliases Xh; written after Xh's last read
  f16* Wqkv_t = (f16*)(ws + 8388608);
  f16* Wout_t = (f16*)(ws + 14680064);
  f16* Qw     = (f16*)(ws + 16777216);
  f16* Kw     = (f16*)(ws + 25165824);
  f16* Vp     = (f16*)(ws + 33554432);
  f16* Ow     = (f16*)(ws + 41943040);
  float* btab = (float*)(ws + 50331648);

  cast_x_kernel<<<4096, 256, 0, stream>>>(X, Xh);
  transpose_cast_kernel<<<dim3(96, 32), 256, 0, stream>>>(Wqkv, Wqkv_t, 1024, 3072);
  transpose_cast_kernel<<<dim3(32, 32), 256, 0, stream>>>(Wout, Wout_t, 1024, 1024);
  bias_table_kernel<<<16, 256, 0, stream>>>(rel, btab);
  gemm_qkv_kernel<<<dim3(24, 32), 256, 0, stream>>>(Xh, Wqkv_t, Qw, Kw, Vp);
  repack_k_kernel<<<2048, 256, 0, stream>>>(Kw, Kp);
  attn_kernel<<<dim3(32, 32), 256, 0, stream>>>(Qw, Kp, Vp, btab, Ow);
  gemm_out_kernel<<<dim3(8, 32), 256, 0, stream>>>(Ow, Wout_t, (float*)d_out);
}

// Round 6
// 223.597 us; speedup vs baseline: 2.1775x; 1.0479x over previous
//
#include <hip/hip_runtime.h>
#include <hip/hip_bf16.h>
#include <math.h>

typedef _Float16 f16;
typedef __attribute__((ext_vector_type(8))) _Float16 f16x8;
typedef __attribute__((ext_vector_type(4))) _Float16 f16x4;
typedef __attribute__((ext_vector_type(4))) float f32x4;

#define EMBED 1024
#define NHEADS 16
#define HDIM 64
#define BATCH 2
#define SEQ 2048
#define BS 4096  // BATCH*SEQ
#define LOG2E 1.4426950408889634f

// ---------------- ws layout (bytes) ----------------
// Xh:      0         (BS*EMBED f16 = 8388608)   -- consumed by gemm_qkv, then
// Kp:      0         ALIASES Xh (8388608 B)     -- written by repack_k afterwards
// Wqkv_t:  8388608   (3072*1024 f16 = 6291456)
// Wout_t:  14680064  (1024*1024 f16 = 2097152)
// Qw:      16777216  [bh][s][d], pre-scaled by log2e
// Kw:      25165824  [bh][s][d] raw
// Vp:      33554432  fragment-packed: [bh][kt32][c4][jp2][lane64][8] f16
// Ow:      41943040  ([B][S][H*64] f16)
// btab:    50331648  (16*4095 f32, pre-scaled by log2e)
// total ~50.6 MB (proven footprint)

__device__ __forceinline__ f32x4 mfma16x32(f16x8 a, f16x8 b, f32x4 c) {
  return __builtin_amdgcn_mfma_f32_16x16x32_f16(a, b, c, 0, 0, 0);
}
__device__ __forceinline__ f32x4 mfma16x16(f16x4 a, f16x4 b, f32x4 c) {
  return __builtin_amdgcn_mfma_f32_16x16x16f16(a, b, c, 0, 0, 0);
}
// async global->LDS, 16 B per lane; LDS dest = wave-uniform base + lane*16
__device__ __forceinline__ void gload_lds16(const f16* __restrict__ g, f16* l) {
  __builtin_amdgcn_global_load_lds(
      (const __attribute__((address_space(1))) void*)g,
      (__attribute__((address_space(3))) void*)l, 16, 0, 0);
}

// ------------- fused prep: cast X | transpose Wqkv | transpose Wout | bias table -------------
// blockIdx.x ranges: [0,4096) cast, [4096,7168) t_qkv, [7168,8192) t_out, [8192,8208) bias
__global__ void prep_kernel(const float* __restrict__ X, const float* __restrict__ Wqkv,
                            const float* __restrict__ Wout, const float* __restrict__ rel_emb,
                            f16* __restrict__ Xh, f16* __restrict__ Wqkv_t,
                            f16* __restrict__ Wout_t, float* __restrict__ btab) {
  __shared__ float tile[32][33];
  int bid = blockIdx.x, tid = threadIdx.x;
  if (bid < 4096) {
    int i = (bid * 256 + tid) * 4;
    float4 v = *(const float4*)(X + i);
    f16x4 o = { (f16)v.x, (f16)v.y, (f16)v.z, (f16)v.w };
    *(f16x4*)(Xh + i) = o;
  } else if (bid < 8192) {
    const float* in;
    f16* out;
    int N, idx;
    if (bid < 7168) { in = Wqkv; out = Wqkv_t; N = 3072; idx = bid - 4096; }
    else            { in = Wout; out = Wout_t; N = 1024; idx = bid - 7168; }
    int nt = N / 32;
    int n0 = (idx % nt) * 32, k0 = (idx / nt) * 32;
    int tx = tid & 31, ty = tid >> 5;
#pragma unroll
    for (int r = ty; r < 32; r += 8) tile[r][tx] = in[(size_t)(k0 + r) * N + n0 + tx];
    __syncthreads();
#pragma unroll
    for (int r = ty; r < 32; r += 8) out[(size_t)(n0 + r) * 1024 + k0 + tx] = (f16)tile[tx][r];
  } else {
    int idx = (bid - 8192) * 256 + tid;  // 0..4094
    if (idx >= 4095) return;
    int rp = idx - 2047;
    int rb = rp > 0 ? 16 : 0;
    int arp = rp < 0 ? -rp : rp;
    int loc;
    if (arp < 8) {
      loc = arp;
    } else {
      float lr = logf((float)arp * 0.125f) * (1.0f / 2.7725887222397811f);
      int t = 8 + (int)(lr * 8.0f);
      loc = t < 15 ? t : 15;
    }
    int bucket = rb + loc;
#pragma unroll
    for (int h = 0; h < 16; h++) btab[h * 4095 + idx] = rel_emb[bucket * 16 + h] * LOG2E;
  }
}

// ------------- shared GEMM core (m97-style): C[128x128] = A[MxK] * Bt[NxK]^T -------------
__device__ __forceinline__ void gemm_core(const f16* __restrict__ A, const f16* __restrict__ Bt,
                                          int m0, int n0, int Kdim, f32x4 (&acc)[4][4]) {
  __shared__ __align__(16) f16 As[128 * 32];  // [m][k], 64 B rows, no pad
  __shared__ __align__(16) f16 Bs[128 * 32];  // [n][k]

  int tid = threadIdx.x;
  int lane = tid & 63, wave = tid >> 6;
  int l15 = lane & 15, quad = lane >> 4;
  int wr = (wave >> 1) * 64, wc = (wave & 1) * 64;
  int rowl = lane >> 2;          // 0..15: 4 lanes per 64-B row
  int col8 = (lane & 3) * 8;     // f16 offset of this lane's 16-B chunk

#pragma unroll
  for (int i = 0; i < 4; i++)
#pragma unroll
    for (int j = 0; j < 4; j++) acc[i][j] = f32x4{0.f, 0.f, 0.f, 0.f};

  for (int kt = 0; kt < Kdim / 32; kt++) {
    int kk = kt * 32;
#pragma unroll
    for (int c = 0; c < 2; c++) {
      int row = wave * 32 + c * 16 + rowl;
      gload_lds16(A + (size_t)(m0 + row) * Kdim + kk + col8, &As[(wave * 32 + c * 16) * 32]);
      gload_lds16(Bt + (size_t)(n0 + row) * Kdim + kk + col8, &Bs[(wave * 32 + c * 16) * 32]);
    }
    __syncthreads();
    f16x8 af[4], bf[4];
#pragma unroll
    for (int i = 0; i < 4; i++) af[i] = *(const f16x8*)(&As[(wr + i * 16 + l15) * 32 + quad * 8]);
#pragma unroll
    for (int j = 0; j < 4; j++) bf[j] = *(const f16x8*)(&Bs[(wc + j * 16 + l15) * 32 + quad * 8]);
#pragma unroll
    for (int i = 0; i < 4; i++)
#pragma unroll
      for (int j = 0; j < 4; j++) acc[i][j] = mfma16x32(af[i], bf[j], acc[i][j]);
    __syncthreads();
  }
}

// ------------- GEMM1: qkv = Xh @ Wqkv_t^T; Q scaled by log2e; V fragment-packed -------------
__global__ __launch_bounds__(256, 2) void gemm_qkv_kernel(
    const f16* __restrict__ Xh, const f16* __restrict__ Wt,
    f16* __restrict__ Q, f16* __restrict__ K_, f16* __restrict__ Vp) {
  f32x4 acc[4][4];
  int m0 = blockIdx.y * 128, n0 = blockIdx.x * 128;
  gemm_core(Xh, Wt, m0, n0, 1024, acc);

  int lane = threadIdx.x & 63, wave = threadIdx.x >> 6;
  int l15 = lane & 15, quad = lane >> 4;
  int wr = (wave >> 1) * 64, wc = (wave & 1) * 64;
  int nq = n0 + wc;          // 64-aligned; uniform per wave quadrant
  int which = nq >> 10;
  int h = (nq >> 6) & 15;
  int b = m0 >> 11;          // 128-tile never crosses batch boundary

  if (which == 2) {
    // Vp[bh][kt][c=i][jp][lane][8]: elements (d=(2jp+half)*16+l15, s=..i*16+quad*4+r)
    int s0 = (m0 & 2047) + wr;  // 64-aligned
    f16* vbase = Vp + (size_t)(b * 16 + h) * 131072 + (size_t)(s0 >> 6) * 4096;
#pragma unroll
    for (int i = 0; i < 4; i++) {
#pragma unroll
      for (int jp = 0; jp < 2; jp++) {
        f16x8 pk = { (f16)acc[i][2 * jp][0],     (f16)acc[i][2 * jp][1],
                     (f16)acc[i][2 * jp][2],     (f16)acc[i][2 * jp][3],
                     (f16)acc[i][2 * jp + 1][0], (f16)acc[i][2 * jp + 1][1],
                     (f16)acc[i][2 * jp + 1][2], (f16)acc[i][2 * jp + 1][3] };
        *(f16x8*)(vbase + (i * 2 + jp) * 512 + lane * 8) = pk;
      }
    }
  } else {
    f16* base = (which == 0) ? Q : K_;
    float sc = (which == 0) ? LOG2E : 1.0f;
#pragma unroll
    for (int i = 0; i < 4; i++) {
#pragma unroll
      for (int j = 0; j < 4; j++) {
        int d = j * 16 + l15;
#pragma unroll
        for (int r = 0; r < 4; r++) {
          int m = m0 + wr + i * 16 + quad * 4 + r;
          int s = m & 2047;
          base[(((size_t)(b * 16 + h) * 2048 + s) << 6) + d] = (f16)(acc[i][j][r] * sc);
        }
      }
    }
  }
}

// ------------- repack K into fragment order: Kp[bh][kt][c][t][lane][8] -------------
__global__ void repack_k_kernel(const f16* __restrict__ Kw, f16* __restrict__ Kp) {
  int o = blockIdx.x * 256 + threadIdx.x;   // out-chunk index, 524288 total
  int lane = o & 63;
  int ct = (o >> 6) & 7;                    // c*2 + t
  int kt = (o >> 9) & 31;
  int bh = o >> 14;
  int c = ct >> 1, t = ct & 1;
  int l15 = lane & 15, quad = lane >> 4;
  int s = kt * 64 + c * 16 + l15;
  f16x8 v = *(const f16x8*)(Kw + ((size_t)(bh * 2048 + s) << 6) + t * 32 + quad * 8);
  *(f16x8*)(Kp + (size_t)o * 8) = v;        // perfectly coalesced write
}

// ------------- flash attention -------------
// S^T per tile: mfma(kf,qf) -> C[key][q]; C-frag of S^T == A-frag of P for 16x16x16 PV.
__global__ __launch_bounds__(256, 4) void attn_kernel(
    const f16* __restrict__ Q, const f16* __restrict__ Kp, const f16* __restrict__ Vp,
    const float* __restrict__ btab, f16* __restrict__ O) {
  __shared__ float bias_lds[2112];   // scalar reads: conflict-free by construction

  int qt = blockIdx.x, bh = blockIdx.y;
  int qbase = qt * 64;
  int h = bh & 15, b = bh >> 4;
  int tid = threadIdx.x, lane = tid & 63, wave = tid >> 6;
  int l15 = lane & 15, quad = lane >> 4;

  const float* brow = btab + h * 4095 + (1984 - qbase);
  for (int i = tid; i < 2111; i += 256) bias_lds[i] = brow[i];

  // Q fragments (B-operand of S^T mfma): B[n=q(l15)][k=d]
  const f16* qptr = Q + ((size_t)bh * 2048 + qbase + wave * 16 + l15) * 64 + quad * 8;
  f16x8 qf0 = *(const f16x8*)(qptr);
  f16x8 qf1 = *(const f16x8*)(qptr + 32);

  f32x4 accO[4] = {};                // O[q=quad*4+r][d=dblk*16+l15]
  float m_i = -INFINITY, l_i = 0.f;  // per-lane state for q = l15 (log2 space)

  // centered pointers: slot byte offsets become immediates within +-3584
  const f16* kc = Kp + (size_t)bh * 131072 + 1792;
  const f16* vc = Vp + (size_t)bh * 131072 + 1792;
  const int voff = lane * 8;
  const int bofs = quad * 4 - wave * 16 - l15 + 63;

  __syncthreads();

  for (int kt = 0; kt < 32; kt++) {
    const float* bb = &bias_lds[kt * 64 + bofs];
    f32x4 scT[4];
#pragma unroll
    for (int c = 0; c < 4; c++) {
      scT[c] = f32x4{ bb[c * 16], bb[c * 16 + 1], bb[c * 16 + 2], bb[c * 16 + 3] };
      f16x8 kf0 = *(const f16x8*)(kc + ((c * 2 + 0) * 512 - 1792) + voff);
      f16x8 kf1 = *(const f16x8*)(kc + ((c * 2 + 1) * 512 - 1792) + voff);
      scT[c] = mfma16x32(kf0, qf0, scT[c]);
      scT[c] = mfma16x32(kf1, qf1, scT[c]);
    }
    // V fragments early so vmcnt overlaps softmax VALU
    f16x8 vf8[4][2];
#pragma unroll
    for (int c = 0; c < 4; c++)
#pragma unroll
      for (int jp = 0; jp < 2; jp++)
        vf8[c][jp] = *(const f16x8*)(vc + ((c * 2 + jp) * 512 - 1792) + voff);
    // per-lane partial max over this wave-tile
    float mp0 = fmaxf(fmaxf(scT[0][0], scT[0][1]), fmaxf(scT[0][2], scT[0][3]));
    float mp1 = fmaxf(fmaxf(scT[1][0], scT[1][1]), fmaxf(scT[1][2], scT[1][3]));
    float mp2 = fmaxf(fmaxf(scT[2][0], scT[2][1]), fmaxf(scT[2][2], scT[2][3]));
    float mp3 = fmaxf(fmaxf(scT[3][0], scT[3][1]), fmaxf(scT[3][2], scT[3][3]));
    float mp = fmaxf(fmaxf(mp0, mp1), fmaxf(mp2, mp3));
    // guarded online-max update: skip all rescale work when no lane exceeds m_i
    if (__any(mp > m_i)) {
      float mx = fmaxf(mp, __shfl_xor(mp, 16));
      mx = fmaxf(mx, __shfl_xor(mx, 32));
      float mn = fmaxf(m_i, mx);
      float alpha = exp2f(m_i - mn);
      m_i = mn;
      l_i *= alpha;
      float arow[4];
#pragma unroll
      for (int r = 0; r < 4; r++) arow[r] = __shfl(alpha, quad * 4 + r);
#pragma unroll
      for (int d = 0; d < 4; d++)
#pragma unroll
        for (int r = 0; r < 4; r++) accO[d][r] *= arow[r];
    }
    float mx = m_i;
    f16x4 p[4];
    float rc[4];
#pragma unroll
    for (int c = 0; c < 4; c++) {
      float e0 = exp2f(scT[c][0] - mx);
      float e1 = exp2f(scT[c][1] - mx);
      float e2 = exp2f(scT[c][2] - mx);
      float e3 = exp2f(scT[c][3] - mx);
      rc[c] = (e0 + e1) + (e2 + e3);
      p[c][0] = (f16)e0; p[c][1] = (f16)e1; p[c][2] = (f16)e2; p[c][3] = (f16)e3;
    }
    float rs = (rc[0] + rc[1]) + (rc[2] + rc[3]);
    rs += __shfl_xor(rs, 16);
    rs += __shfl_xor(rs, 32);
    l_i += rs;
    // PV: accO[dblk] += P (A-frag = reinterpreted scT) x V (fragment-packed)
#pragma unroll
    for (int c = 0; c < 4; c++) {
#pragma unroll
      for (int jp = 0; jp < 2; jp++) {
        f16x4 vlo = __builtin_shufflevector(vf8[c][jp], vf8[c][jp], 0, 1, 2, 3);
        f16x4 vhi = __builtin_shufflevector(vf8[c][jp], vf8[c][jp], 4, 5, 6, 7);
        accO[2 * jp]     = mfma16x16(p[c], vlo, accO[2 * jp]);
        accO[2 * jp + 1] = mfma16x16(p[c], vhi, accO[2 * jp + 1]);
      }
    }
    kc += 4096;
    vc += 4096;
  }

  // epilogue: O[q][d] / l  -> Ow[b][s][h*64+d]
  float linv = 1.0f / l_i;
  float lrow[4];
#pragma unroll
  for (int r = 0; r < 4; r++) lrow[r] = __shfl(linv, quad * 4 + r);
#pragma unroll
  for (int dblk = 0; dblk < 4; dblk++) {
#pragma unroll
    for (int r = 0; r < 4; r++) {
      int q = qbase + wave * 16 + quad * 4 + r;
      O[((size_t)(b * 2048 + q) << 10) + h * 64 + dblk * 16 + l15] = (f16)(accO[dblk][r] * lrow[r]);
    }
  }
}

// ------------- GEMM2: out = Ow @ Wout_t^T (fp32 out) -------------
__global__ __launch_bounds__(256, 2) void gemm_out_kernel(
    const f16* __restrict__ Oh, const f16* __restrict__ Wt, float* __restrict__ out) {
  f32x4 acc[4][4];
  int m0 = blockIdx.y * 128, n0 = blockIdx.x * 128;
  gemm_core(Oh, Wt, m0, n0, 1024, acc);

  int lane = threadIdx.x & 63, wave = threadIdx.x >> 6;
  int l15 = lane & 15, quad = lane >> 4;
  int wr = (wave >> 1) * 64, wc = (wave & 1) * 64;
#pragma unroll
  for (int i = 0; i < 4; i++) {
#pragma unroll
    for (int j = 0; j < 4; j++) {
      int n = n0 + wc + j * 16 + l15;
#pragma unroll
      for (int r = 0; r < 4; r++) {
        int m = m0 + wr + i * 16 + quad * 4 + r;
        out[((size_t)m << 10) + n] = acc[i][j][r];
      }
    }
  }
}

extern "C" void kernel_launch(void* const* d_in, const int* in_sizes, int n_in,
                              void* d_out, int out_size, void* d_ws, size_t ws_size,
                              hipStream_t stream) {
  const float* X = (const float*)d_in[0];     // (2,2048,1024)
  const float* Wqkv = (const float*)d_in[1];  // (1024,3072)
  const float* Wout = (const float*)d_in[2];  // (1024,1024)
  const float* rel = (const float*)d_in[3];   // (32,16)

  char* ws = (char*)d_ws;
  f16* Xh     = (f16*)(ws + 0);
  f16* Kp     = (f16*)(ws + 0);         // aliases Xh; written after Xh's last read
  f16* Wqkv_t = (f16*)(ws + 8388608);
  f16* Wout_t = (f16*)(ws + 14680064);
  f16* Qw     = (f16*)(ws + 16777216);
  f16* Kw     = (f16*)(ws + 25165824);
  f16* Vp     = (f16*)(ws + 33554432);
  f16* Ow     = (f16*)(ws + 41943040);
  float* btab = (float*)(ws + 50331648);

  prep_kernel<<<8208, 256, 0, stream>>>(X, Wqkv, Wout, rel, Xh, Wqkv_t, Wout_t, btab);
  gemm_qkv_kernel<<<dim3(24, 32), 256, 0, stream>>>(Xh, Wqkv_t, Qw, Kw, Vp);
  repack_k_kernel<<<2048, 256, 0, stream>>>(Kw, Kp);
  attn_kernel<<<dim3(32, 32), 256, 0, stream>>>(Qw, Kp, Vp, btab, Ow);
  gemm_out_kernel<<<dim3(8, 32), 256, 0, stream>>>(Ow, Wout_t, (float*)d_out);
}